// Round 1
// baseline (378.699 us; speedup 1.0000x reference)
//
#include <hip/hip_runtime.h>

// Stencil gather: out[b,j,k,{center,up,right,down,left}], edge-replicated.
// B=16, H=1024, W=1024, f32. 64 MiB read + 320 MiB write -> ~65-85 us floor
// at the ~6.4 TB/s the harness's own poison-fill demonstrates.
//
// Round 2 (this version): graph dur 367us = ~209us poison-fill (harness,
// fixed) + ~158us stencil (~2.6 TB/s effective, 2x off roofline). Theory:
// single-row blocks starve the write pipe (5-store burst gated behind a
// load+barrier convoy, 16384 short blocks churning, every input row read
// 3x by 3 different blocks). Fix: persistent fully-resident blocks.
//
//   grid = 2048 blocks = exactly 8/CU at 20 KiB LDS -> all resident.
//   Each block owns an 8-row band of one image (8 | 1024, bands never
//   cross images). Rolling registers up/cur/dwn hold rows j-1,j,j+1 of
//   the thread's 4-column strip; each input row is loaded ONCE per block
//   (10 rows per 8 output rows). The next down-row is prefetched 2 rows
//   ahead so global-load latency sits under the store phase. Per wave the
//   store side is now a continuous stream of 40 coalesced nt float4s.
//
// LDS layout per row (verified correct in round 1, absmax 0.0):
//   thread i -> 20 floats at lds+80B*i, pixel-major channel-minor:
//   [c.x,u.x,c.y,d.x,lx | c.y,u.y,c.z,d.y,c.x | c.z,u.z,c.w,d.z,c.y |
//    c.w,u.w,rw,d.w,c.z]
//   Phase-1 writes: start bank 20i mod 32 -> lanes 0..7 cover all 32
//   banks, conflict-free. Phase-2 reads ls[i+256r]: bank 4i mod 32,
//   conflict-free. Stores lane-consecutive float4 -> fully coalesced.

typedef float f4 __attribute__((ext_vector_type(4)));

constexpr int ROWS = 8;

__global__ __launch_bounds__(256) void stencil5_kernel(
    const float* __restrict__ in, float* __restrict__ out) {
    constexpr int W = 1024;
    constexpr int H = 1024;

    __shared__ float lds[256 * 20];   // 20 KiB -> 8 blocks/CU

    const int i  = threadIdx.x;
    const int k0 = i << 2;                 // starting column of this strip
    const int g0 = blockIdx.x * ROWS;      // first global row of the band
    const int j0 = g0 & (H - 1);           // row within image
    const long imgbase = (long)(g0 - j0) << 10;

    const float* pk = in + imgbase + k0;   // this image, this column strip

    // Rolling rows j-1, j, j+1 (edge-replicated at image borders).
    float4 up  = *(const float4*)(pk + ((long)(j0 > 0 ? j0 - 1 : 0) << 10));
    float4 cur = *(const float4*)(pk + ((long)j0 << 10));
    float4 dwn = *(const float4*)(pk + ((long)(j0 + 1) << 10)); // j0+1 <= H-1 always

    f4* o = (f4*)(out + ((long)g0 << 10) * 5);
    float4* l = (float4*)(lds + i * 20);
    const f4* ls = (const f4*)lds;

    #pragma unroll
    for (int r = 0; r < ROWS; ++r) {
        const int j = j0 + r;

        // Prefetch row j+2 = next iteration's down-row, clamped at image end.
        const int jn = (j + 2 < H) ? (j + 2) : (H - 1);
        const float4 nxt = *(const float4*)(pk + ((long)jn << 10));

        // Strip-edge left/right neighbors from the center row (L1 hits —
        // same cache lines as cur).
        const float* pc = pk + ((long)j << 10);
        float lx = pc[k0 > 0 ? -1 : 0];
        lx = (k0 > 0) ? lx : cur.x;
        float rw = pc[(k0 + 4 < W) ? 4 : 3];
        rw = (k0 + 4 < W) ? rw : cur.w;

        l[0] = make_float4(cur.x, up.x,  cur.y, dwn.x);
        l[1] = make_float4(lx,    cur.y, up.y,  cur.z);
        l[2] = make_float4(dwn.y, cur.x, cur.z, up.z);
        l[3] = make_float4(cur.w, dwn.z, cur.y, cur.w);
        l[4] = make_float4(up.w,  rw,    dwn.w, cur.z);

        __syncthreads();

        // Coalesced streaming store of this row's 20 KiB.
        #pragma unroll
        for (int s = 0; s < 5; ++s) {
            __builtin_nontemporal_store(ls[i + 256 * s],
                                        o + (long)r * 1280 + i + 256 * s);
        }

        __syncthreads();

        up = cur; cur = dwn; dwn = nxt;
    }
}

extern "C" void kernel_launch(void* const* d_in, const int* in_sizes, int n_in,
                              void* d_out, int out_size, void* d_ws, size_t ws_size,
                              hipStream_t stream) {
    const float* in = (const float*)d_in[0];
    float* out = (float*)d_out;

    const int n = in_sizes[0];            // B*H*W = 16*1024*1024
    const int rows = n >> 10;             // 16384 image rows
    const int blocks = rows / ROWS;       // 2048 = 8 per CU, fully resident

    stencil5_kernel<<<blocks, 256, 0, stream>>>(in, out);
}